// Round 1
// baseline (547.826 us; speedup 1.0000x reference)
//
#include <hip/hip_runtime.h>
#include <math.h>

#define L_SEQ 16384
#define BATCH 2
#define BL (BATCH * L_SEQ)      // 32768
#define DIN 256                 // D_INNER
#define DIMC 128                // DIM
#define NST 16                  // D_STATE
#define DTR 8                   // DT_RANK
#define CL 32                   // chunk length for scan
#define NC (L_SEQ / CL)         // 512 chunks per batch

// ---------------- K0: layernorm stats (mean, rstd) per position ----------------
__global__ __launch_bounds__(256) void k_ln_stats(const float* __restrict__ x,
                                                  float* __restrict__ mu,
                                                  float* __restrict__ rstd) {
    int p = blockIdx.x * 256 + threadIdx.x;   // 0..BL-1
    int b = p / L_SEQ, l = p % L_SEQ;
    const float* xb = x + (size_t)b * DIMC * L_SEQ + l;
    float s = 0.f, s2 = 0.f;
    for (int c = 0; c < DIMC; c++) {
        float v = xb[(size_t)c * L_SEQ];
        s += v; s2 += v * v;
    }
    float m = s * (1.f / DIMC);
    float var = s2 * (1.f / DIMC) - m * m;
    mu[p] = m;
    rstd[p] = rsqrtf(var + 1e-6f);
}

// ---------------- K1: fused LN + in_proj GEMM: xz(BL x 512) = xn(BL x 128) @ W1^T ----------------
__global__ __launch_bounds__(256) void k_inproj(const float* __restrict__ x,
                                                const float* __restrict__ mu,
                                                const float* __restrict__ rstd,
                                                const float* __restrict__ nw,
                                                const float* __restrict__ nb,
                                                const float* __restrict__ w1,
                                                float* __restrict__ xz) {
    // grid: (BL/64, 512/64)
    __shared__ float As[128 * 65];  // [c][pos_local], ld=65 -> conflict-free
    __shared__ float Bs[128 * 65];  // [c][o_local]
    int bl0 = blockIdx.x * 64;
    int b = bl0 / L_SEQ;
    int l0 = bl0 % L_SEQ;
    int o0 = blockIdx.y * 64;
    int tid = threadIdx.x;

    for (int idx = tid; idx < 128 * 64; idx += 256) {
        int c = idx >> 6, i = idx & 63;
        float v = x[((size_t)b * DIMC + c) * L_SEQ + l0 + i];
        int p = bl0 + i;
        As[c * 65 + i] = (v - mu[p]) * rstd[p] * nw[c] + nb[c];
    }
    for (int idx = tid; idx < 64 * 128; idx += 256) {
        int o = idx >> 7, c = idx & 127;
        Bs[c * 65 + o] = w1[(o0 + o) * 128 + c];
    }
    __syncthreads();

    int tx = tid & 15, ty = tid >> 4;   // tx -> output dim o (coalesced writes), ty -> position
    float acc[4][4] = {};
    for (int c = 0; c < 128; c++) {
        float a[4], bb[4];
        #pragma unroll
        for (int ii = 0; ii < 4; ii++) a[ii] = As[c * 65 + ty * 4 + ii];
        #pragma unroll
        for (int jj = 0; jj < 4; jj++) bb[jj] = Bs[c * 65 + tx * 4 + jj];
        #pragma unroll
        for (int ii = 0; ii < 4; ii++)
            #pragma unroll
            for (int jj = 0; jj < 4; jj++) acc[ii][jj] += a[ii] * bb[jj];
    }
    #pragma unroll
    for (int ii = 0; ii < 4; ii++) {
        int p = bl0 + ty * 4 + ii;
        float4 v = make_float4(acc[ii][0], acc[ii][1], acc[ii][2], acc[ii][3]);
        *(float4*)&xz[(size_t)p * 512 + o0 + tx * 4] = v;
    }
}

// ---------------- K2: causal depthwise conv (k=4) + silu -> x_in ----------------
__global__ __launch_bounds__(256) void k_conv(const float* __restrict__ xz,
                                              const float* __restrict__ cw,
                                              const float* __restrict__ cb,
                                              float* __restrict__ xin) {
    int p = blockIdx.x;          // 0..BL-1
    int d = threadIdx.x;         // 0..255
    int b = p / L_SEQ, t = p % L_SEQ;
    float acc = cb[d];
    #pragma unroll
    for (int k = 0; k < 4; k++) {
        int tt = t + k - 3;
        if (tt >= 0) acc += xz[((size_t)(b * L_SEQ + tt)) * 512 + d] * cw[d * 4 + k];
    }
    float sig = 1.f / (1.f + __expf(-acc));
    xin[(size_t)p * 256 + d] = acc * sig;
}

// ---------------- K3: x_proj (256->40) + dt_proj (8->256) + softplus ----------------
__global__ __launch_bounds__(256) void k_xproj(const float* __restrict__ xin,
                                               const float* __restrict__ wx,
                                               const float* __restrict__ wdt,
                                               const float* __restrict__ bdt,
                                               float* __restrict__ dtb,
                                               float* __restrict__ Bmb,
                                               float* __restrict__ Cmb) {
    __shared__ float Xs[32 * 260];  // 32 positions x 256 (pad 260)
    __shared__ float Xd[32 * 44];   // 32 positions x 40 (pad 44)
    int bl0 = blockIdx.x * 32;
    int tid = threadIdx.x;

    for (int idx = tid; idx < 32 * 256; idx += 256) {
        int p = idx >> 8, c = idx & 255;
        Xs[p * 260 + c] = xin[(size_t)(bl0 + p) * 256 + c];
    }
    __syncthreads();

    for (int idx = tid; idx < 32 * 40; idx += 256) {
        int p = idx / 40, o = idx % 40;
        const float* w = wx + o * 256;
        const float* xr = Xs + p * 260;
        float acc = 0.f;
        for (int c = 0; c < 256; c++) acc += xr[c] * w[c];
        Xd[p * 44 + o] = acc;
    }
    __syncthreads();

    // dt: each thread owns one d, loops positions
    int d = tid;
    float bias = bdt[d];
    float w8[8];
    #pragma unroll
    for (int r = 0; r < 8; r++) w8[r] = wdt[d * 8 + r];
    for (int p = 0; p < 32; p++) {
        float acc = bias;
        #pragma unroll
        for (int r = 0; r < 8; r++) acc += Xd[p * 44 + r] * w8[r];
        float sp = (acc > 20.f) ? acc : log1pf(__expf(acc));
        dtb[(size_t)(bl0 + p) * 256 + d] = sp;
    }

    for (int idx = tid; idx < 32 * 32; idx += 256) {
        int p = idx >> 5, j = idx & 31;
        float v = Xd[p * 44 + 8 + j];
        if (j < 16) Bmb[(size_t)(bl0 + p) * 16 + j] = v;
        else        Cmb[(size_t)(bl0 + p) * 16 + (j - 16)] = v;
    }
}

// ---------------- K4a: scan phase 1 — per-chunk products & local states ----------------
__global__ __launch_bounds__(256) void k_scan1(const float* __restrict__ dtb,
                                               const float* __restrict__ xin,
                                               const float* __restrict__ Bmb,
                                               const float* __restrict__ Alog,
                                               float* __restrict__ Pb,
                                               float* __restrict__ Sb) {
    int blk = blockIdx.x;            // BATCH*NC blocks
    int b = blk / NC, ch = blk % NC;
    int d = threadIdx.x;
    int t0 = ch * CL;
    __shared__ float Bs[CL * 16];
    for (int idx = threadIdx.x; idx < CL * 16; idx += 256)
        Bs[idx] = Bmb[((size_t)(b * L_SEQ + t0)) * 16 + idx];
    float Ar[16];
    #pragma unroll
    for (int n = 0; n < 16; n++) Ar[n] = -__expf(Alog[d * 16 + n]);
    float P[16], S[16];
    #pragma unroll
    for (int n = 0; n < 16; n++) { P[n] = 1.f; S[n] = 0.f; }
    __syncthreads();
    for (int i = 0; i < CL; i++) {
        size_t p = (size_t)(b * L_SEQ + t0 + i);
        float dtv = dtb[p * 256 + d];
        float xv  = xin[p * 256 + d];
        float du = dtv * xv;
        #pragma unroll
        for (int n = 0; n < 16; n++) {
            float a = __expf(dtv * Ar[n]);
            P[n] *= a;
            S[n] = a * S[n] + du * Bs[i * 16 + n];
        }
    }
    size_t base = ((size_t)(b * NC + ch) * 16) * 256 + d;
    #pragma unroll
    for (int n = 0; n < 16; n++) {
        Pb[base + (size_t)n * 256] = P[n];
        Sb[base + (size_t)n * 256] = S[n];
    }
}

// ---------------- K4b: scan phase 2 — sequential over chunks, Sb becomes h_start ----------------
__global__ __launch_bounds__(256) void k_scan2(const float* __restrict__ Pb,
                                               float* __restrict__ Sb) {
    int id = blockIdx.x * 256 + threadIdx.x;  // 0..8191: (b,n,d)
    int d = id & 255;
    int n = (id >> 8) & 15;
    int b = id >> 12;
    float h = 0.f;
    for (int c = 0; c < NC; c++) {
        size_t ix = (((size_t)(b * NC + c) * 16) + n) * 256 + d;
        float Pv = Pb[ix];
        float Sv = Sb[ix];
        Sb[ix] = h;          // h_start for chunk c
        h = Pv * h + Sv;
    }
}

// ---------------- K4c: scan phase 3 — replay chunk from h_start, fuse D-skip + silu(z) gate ----------------
__global__ __launch_bounds__(256) void k_scan3(const float* __restrict__ dtb,
                                               const float* __restrict__ xin,
                                               const float* __restrict__ Bmb,
                                               const float* __restrict__ Cmb,
                                               const float* __restrict__ Alog,
                                               const float* __restrict__ Sb,
                                               const float* __restrict__ Dp,
                                               const float* __restrict__ xz,
                                               float* __restrict__ yg) {
    int blk = blockIdx.x;
    int b = blk / NC, ch = blk % NC;
    int d = threadIdx.x;
    int t0 = ch * CL;
    __shared__ float Bs[CL * 16], Cs[CL * 16];
    for (int idx = threadIdx.x; idx < CL * 16; idx += 256) {
        Bs[idx] = Bmb[((size_t)(b * L_SEQ + t0)) * 16 + idx];
        Cs[idx] = Cmb[((size_t)(b * L_SEQ + t0)) * 16 + idx];
    }
    float Ar[16], h[16];
    #pragma unroll
    for (int n = 0; n < 16; n++) Ar[n] = -__expf(Alog[d * 16 + n]);
    size_t base = ((size_t)(b * NC + ch) * 16) * 256 + d;
    #pragma unroll
    for (int n = 0; n < 16; n++) h[n] = Sb[base + (size_t)n * 256];
    float Dv = Dp[d];
    __syncthreads();
    for (int i = 0; i < CL; i++) {
        size_t p = (size_t)(b * L_SEQ + t0 + i);
        float dtv = dtb[p * 256 + d];
        float xv  = xin[p * 256 + d];
        float du = dtv * xv;
        float y = 0.f;
        #pragma unroll
        for (int n = 0; n < 16; n++) {
            float a = __expf(dtv * Ar[n]);
            h[n] = a * h[n] + du * Bs[i * 16 + n];
            y += h[n] * Cs[i * 16 + n];
        }
        float zv = xz[p * 512 + 256 + d];
        float sig = 1.f / (1.f + __expf(-zv));
        yg[p * 256 + d] = (y + xv * Dv) * (zv * sig);
    }
}

// ---------------- K5: out_proj GEMM with transposed output: out[b][c][t] = yg[b][t][:] . Wo[c][:] ----------------
__global__ __launch_bounds__(256) void k_outproj(const float* __restrict__ yg,
                                                 const float* __restrict__ wo,
                                                 float* __restrict__ out) {
    // grid: (BL/64, 128/64)
    __shared__ float As[64 * 65];  // [k][t_local]
    __shared__ float Bs[64 * 65];  // [k][c_local]
    int bl0 = blockIdx.x * 64;
    int b = bl0 / L_SEQ;
    int t0 = bl0 % L_SEQ;
    int c0 = blockIdx.y * 64;
    int tid = threadIdx.x;
    int tx = tid & 15, ty = tid >> 4;   // tx -> t (coalesced out writes), ty -> c

    float acc[4][4] = {};               // [t_off][c_off]
    for (int k0 = 0; k0 < 256; k0 += 64) {
        __syncthreads();
        for (int idx = tid; idx < 64 * 64; idx += 256) {
            int t = idx >> 6, kk = idx & 63;
            As[kk * 65 + t] = yg[(size_t)(bl0 + t) * 256 + k0 + kk];
        }
        for (int idx = tid; idx < 64 * 64; idx += 256) {
            int c = idx >> 6, kk = idx & 63;
            Bs[kk * 65 + c] = wo[(c0 + c) * 256 + k0 + kk];
        }
        __syncthreads();
        for (int k = 0; k < 64; k++) {
            float a[4], bb[4];
            #pragma unroll
            for (int ii = 0; ii < 4; ii++) a[ii] = As[k * 65 + tx * 4 + ii];
            #pragma unroll
            for (int jj = 0; jj < 4; jj++) bb[jj] = Bs[k * 65 + ty * 4 + jj];
            #pragma unroll
            for (int ii = 0; ii < 4; ii++)
                #pragma unroll
                for (int jj = 0; jj < 4; jj++) acc[ii][jj] += a[ii] * bb[jj];
        }
    }
    #pragma unroll
    for (int jj = 0; jj < 4; jj++) {
        int c = c0 + ty * 4 + jj;
        float4 v = make_float4(acc[0][jj], acc[1][jj], acc[2][jj], acc[3][jj]);
        *(float4*)&out[((size_t)(b * 128 + c)) * L_SEQ + t0 + tx * 4] = v;
    }
}

extern "C" void kernel_launch(void* const* d_in, const int* in_sizes, int n_in,
                              void* d_out, int out_size, void* d_ws, size_t ws_size,
                              hipStream_t stream) {
    const float* x    = (const float*)d_in[0];
    const float* nw   = (const float*)d_in[1];
    const float* nb   = (const float*)d_in[2];
    const float* w1   = (const float*)d_in[3];
    const float* cw   = (const float*)d_in[4];
    const float* cb   = (const float*)d_in[5];
    const float* wx   = (const float*)d_in[6];
    const float* wdt  = (const float*)d_in[7];
    const float* bdt  = (const float*)d_in[8];
    const float* Alog = (const float*)d_in[9];
    const float* Dp   = (const float*)d_in[10];
    const float* wo   = (const float*)d_in[11];
    float* out = (float*)d_out;

    float* ws   = (float*)d_ws;
    float* xz   = ws;                       // BL*512 = 16,777,216
    float* mu   = xz + (size_t)BL * 512;    // 32768
    float* rstd = mu + BL;                  // 32768
    float* xin  = rstd + BL;                // BL*256 = 8,388,608
    float* dtb  = xin + (size_t)BL * 256;   // 8,388,608
    float* Bmb  = dtb + (size_t)BL * 256;   // 524,288
    float* Cmb  = Bmb + (size_t)BL * 16;    // 524,288
    float* Pb   = Cmb + (size_t)BL * 16;    // 2*NC*16*256 = 4,194,304
    float* Sb   = Pb + (size_t)BATCH * NC * 16 * 256;  // 4,194,304
    float* yg   = Sb + (size_t)BATCH * NC * 16 * 256;  // 8,388,608

    k_ln_stats<<<BL / 256, 256, 0, stream>>>(x, mu, rstd);
    k_inproj<<<dim3(BL / 64, 512 / 64), 256, 0, stream>>>(x, mu, rstd, nw, nb, w1, xz);
    k_conv<<<BL, 256, 0, stream>>>(xz, cw, cb, xin);
    k_xproj<<<BL / 32, 256, 0, stream>>>(xin, wx, wdt, bdt, dtb, Bmb, Cmb);
    k_scan1<<<BATCH * NC, 256, 0, stream>>>(dtb, xin, Bmb, Alog, Pb, Sb);
    k_scan2<<<8192 / 256, 256, 0, stream>>>(Pb, Sb);
    k_scan3<<<BATCH * NC, 256, 0, stream>>>(dtb, xin, Bmb, Cmb, Alog, Sb, Dp, xz, yg);
    k_outproj<<<dim3(BL / 64, 128 / 64), 256, 0, stream>>>(yg, wo, out);
}

// Round 2
// 438.861 us; speedup vs baseline: 1.2483x; 1.2483x over previous
//
#include <hip/hip_runtime.h>
#include <math.h>

#define L_SEQ 16384
#define BATCH 2
#define BL (BATCH * L_SEQ)      // 32768
#define DIN 256                 // D_INNER
#define DIMC 128                // DIM
#define NST 16                  // D_STATE
#define DTR 8                   // DT_RANK
#define CL 32                   // chunk length for scan
#define NC (L_SEQ / CL)         // 512 chunks per batch

// ---------------- K0: layernorm stats (mean, rstd) per position ----------------
__global__ __launch_bounds__(256) void k_ln_stats(const float* __restrict__ x,
                                                  float* __restrict__ mu,
                                                  float* __restrict__ rstd) {
    int p = blockIdx.x * 256 + threadIdx.x;   // 0..BL-1
    int b = p / L_SEQ, l = p % L_SEQ;
    const float* xb = x + (size_t)b * DIMC * L_SEQ + l;
    float s = 0.f, s2 = 0.f;
    for (int c = 0; c < DIMC; c++) {
        float v = xb[(size_t)c * L_SEQ];
        s += v; s2 += v * v;
    }
    float m = s * (1.f / DIMC);
    float var = s2 * (1.f / DIMC) - m * m;
    mu[p] = m;
    rstd[p] = rsqrtf(var + 1e-6f);
}

// ---------------- K1: fused LN + in_proj GEMM: xz(BL x 512) = xn(BL x 128) @ W1^T ----------------
__global__ __launch_bounds__(256) void k_inproj(const float* __restrict__ x,
                                                const float* __restrict__ mu,
                                                const float* __restrict__ rstd,
                                                const float* __restrict__ nw,
                                                const float* __restrict__ nb,
                                                const float* __restrict__ w1,
                                                float* __restrict__ xz) {
    // grid: (BL/64, 512/64)
    __shared__ float As[128 * 65];  // [c][pos_local], ld=65 -> conflict-free
    __shared__ float Bs[128 * 65];  // [c][o_local]
    int bl0 = blockIdx.x * 64;
    int b = bl0 / L_SEQ;
    int l0 = bl0 % L_SEQ;
    int o0 = blockIdx.y * 64;
    int tid = threadIdx.x;

    for (int idx = tid; idx < 128 * 64; idx += 256) {
        int c = idx >> 6, i = idx & 63;
        float v = x[((size_t)b * DIMC + c) * L_SEQ + l0 + i];
        int p = bl0 + i;
        As[c * 65 + i] = (v - mu[p]) * rstd[p] * nw[c] + nb[c];
    }
    for (int idx = tid; idx < 64 * 128; idx += 256) {
        int o = idx >> 7, c = idx & 127;
        Bs[c * 65 + o] = w1[(o0 + o) * 128 + c];
    }
    __syncthreads();

    int tx = tid & 15, ty = tid >> 4;   // tx -> output dim o (coalesced writes), ty -> position
    float acc[4][4] = {};
    for (int c = 0; c < 128; c++) {
        float a[4], bb[4];
        #pragma unroll
        for (int ii = 0; ii < 4; ii++) a[ii] = As[c * 65 + ty * 4 + ii];
        #pragma unroll
        for (int jj = 0; jj < 4; jj++) bb[jj] = Bs[c * 65 + tx * 4 + jj];
        #pragma unroll
        for (int ii = 0; ii < 4; ii++)
            #pragma unroll
            for (int jj = 0; jj < 4; jj++) acc[ii][jj] += a[ii] * bb[jj];
    }
    #pragma unroll
    for (int ii = 0; ii < 4; ii++) {
        int p = bl0 + ty * 4 + ii;
        float4 v = make_float4(acc[ii][0], acc[ii][1], acc[ii][2], acc[ii][3]);
        *(float4*)&xz[(size_t)p * 512 + o0 + tx * 4] = v;
    }
}

// ---------------- K2: causal depthwise conv (k=4) + silu -> x_in ----------------
__global__ __launch_bounds__(256) void k_conv(const float* __restrict__ xz,
                                              const float* __restrict__ cw,
                                              const float* __restrict__ cb,
                                              float* __restrict__ xin) {
    int p = blockIdx.x;          // 0..BL-1
    int d = threadIdx.x;         // 0..255
    int b = p / L_SEQ, t = p % L_SEQ;
    float acc = cb[d];
    #pragma unroll
    for (int k = 0; k < 4; k++) {
        int tt = t + k - 3;
        if (tt >= 0) acc += xz[((size_t)(b * L_SEQ + tt)) * 512 + d] * cw[d * 4 + k];
    }
    float sig = 1.f / (1.f + __expf(-acc));
    xin[(size_t)p * 256 + d] = acc * sig;
}

// ---------------- K3: x_proj GEMM (256->40, padded to 64) + fused dt_proj (8->256) + softplus ----
// x_dbl(BL x 40) = xin(BL x 256) @ wx^T.  Tile: 64 positions x 64 outputs (40 valid), K chunks 128.
// LDS stride 68 keeps 4-float reads 16B-aligned (ds_read_b128) and bank-conflict-free.
__global__ __launch_bounds__(256) void k_xproj(const float* __restrict__ xin,
                                               const float* __restrict__ wx,
                                               const float* __restrict__ wdt,
                                               const float* __restrict__ bdt,
                                               float* __restrict__ dtb,
                                               float* __restrict__ Bmb,
                                               float* __restrict__ Cmb) {
    __shared__ float Xs[128 * 68];  // [c][pos_local]
    __shared__ float Ws[128 * 68];  // [c][o_local] (o >= 40 zero-padded)
    __shared__ float Dt8[64 * 8];   // x_dbl[:, :8] staging for dt_proj
    int bl0 = blockIdx.x * 64;
    int tid = threadIdx.x;
    int tx = tid & 15, ty = tid >> 4;  // tx -> output quad, ty -> position quad

    float acc[4][4] = {};              // [pos_off][o_off]
    for (int c0 = 0; c0 < 256; c0 += 128) {
        __syncthreads();
        for (int idx = tid; idx < 128 * 64; idx += 256) {
            int c = idx & 127, i = idx >> 7;   // lane -> c : coalesced global read
            Xs[c * 68 + i] = xin[(size_t)(bl0 + i) * 256 + c0 + c];
        }
        for (int idx = tid; idx < 128 * 64; idx += 256) {
            int c = idx & 127, o = idx >> 7;
            Ws[c * 68 + o] = (o < 40) ? wx[o * 256 + c0 + c] : 0.f;
        }
        __syncthreads();
        for (int c = 0; c < 128; c++) {
            float a[4], bb[4];
            #pragma unroll
            for (int ii = 0; ii < 4; ii++) a[ii] = Xs[c * 68 + ty * 4 + ii];
            #pragma unroll
            for (int jj = 0; jj < 4; jj++) bb[jj] = Ws[c * 68 + tx * 4 + jj];
            #pragma unroll
            for (int ii = 0; ii < 4; ii++)
                #pragma unroll
                for (int jj = 0; jj < 4; jj++) acc[ii][jj] += a[ii] * bb[jj];
        }
    }

    // Scatter outputs: o in [0,8) -> Dt8 (LDS), [8,24) -> Bm, [24,40) -> Cm
    __syncthreads();
    if (tx < 2) {
        #pragma unroll
        for (int ii = 0; ii < 4; ii++)
            #pragma unroll
            for (int jj = 0; jj < 4; jj++)
                Dt8[(ty * 4 + ii) * 8 + tx * 4 + jj] = acc[ii][jj];
    } else if (tx < 6) {
        #pragma unroll
        for (int ii = 0; ii < 4; ii++) {
            size_t p = (size_t)(bl0 + ty * 4 + ii);
            float4 v = make_float4(acc[ii][0], acc[ii][1], acc[ii][2], acc[ii][3]);
            *(float4*)&Bmb[p * 16 + (tx - 2) * 4] = v;
        }
    } else if (tx < 10) {
        #pragma unroll
        for (int ii = 0; ii < 4; ii++) {
            size_t p = (size_t)(bl0 + ty * 4 + ii);
            float4 v = make_float4(acc[ii][0], acc[ii][1], acc[ii][2], acc[ii][3]);
            *(float4*)&Cmb[p * 16 + (tx - 6) * 4] = v;
        }
    }
    __syncthreads();

    // dt_proj: each thread owns channel d = tid, loops the 64 positions
    int d = tid;
    float bias = bdt[d];
    float w8[8];
    #pragma unroll
    for (int r = 0; r < 8; r++) w8[r] = wdt[d * 8 + r];
    for (int p = 0; p < 64; p++) {
        float4 xa = *(float4*)&Dt8[p * 8];
        float4 xb = *(float4*)&Dt8[p * 8 + 4];
        float a = bias;
        a += xa.x * w8[0] + xa.y * w8[1] + xa.z * w8[2] + xa.w * w8[3];
        a += xb.x * w8[4] + xb.y * w8[5] + xb.z * w8[6] + xb.w * w8[7];
        float sp = (a > 20.f) ? a : log1pf(__expf(a));
        dtb[(size_t)(bl0 + p) * 256 + d] = sp;
    }
}

// ---------------- K4a: scan phase 1 — per-chunk products & local states ----------------
__global__ __launch_bounds__(256) void k_scan1(const float* __restrict__ dtb,
                                               const float* __restrict__ xin,
                                               const float* __restrict__ Bmb,
                                               const float* __restrict__ Alog,
                                               float* __restrict__ Pb,
                                               float* __restrict__ Sb) {
    int blk = blockIdx.x;            // BATCH*NC blocks
    int b = blk / NC, ch = blk % NC;
    int d = threadIdx.x;
    int t0 = ch * CL;
    __shared__ float Bs[CL * 16];
    for (int idx = threadIdx.x; idx < CL * 16; idx += 256)
        Bs[idx] = Bmb[((size_t)(b * L_SEQ + t0)) * 16 + idx];
    float Ar[16];
    #pragma unroll
    for (int n = 0; n < 16; n++) Ar[n] = -__expf(Alog[d * 16 + n]);
    float P[16], S[16];
    #pragma unroll
    for (int n = 0; n < 16; n++) { P[n] = 1.f; S[n] = 0.f; }
    __syncthreads();
    for (int i = 0; i < CL; i++) {
        size_t p = (size_t)(b * L_SEQ + t0 + i);
        float dtv = dtb[p * 256 + d];
        float xv  = xin[p * 256 + d];
        float du = dtv * xv;
        #pragma unroll
        for (int n = 0; n < 16; n++) {
            float a = __expf(dtv * Ar[n]);
            P[n] *= a;
            S[n] = a * S[n] + du * Bs[i * 16 + n];
        }
    }
    size_t base = ((size_t)(b * NC + ch) * 16) * 256 + d;
    #pragma unroll
    for (int n = 0; n < 16; n++) {
        Pb[base + (size_t)n * 256] = P[n];
        Sb[base + (size_t)n * 256] = S[n];
    }
}

// ---------------- K4b: scan phase 2 — sequential over chunks, Sb becomes h_start ----------------
__global__ __launch_bounds__(256) void k_scan2(const float* __restrict__ Pb,
                                               float* __restrict__ Sb) {
    int id = blockIdx.x * 256 + threadIdx.x;  // 0..8191: (b,n,d)
    int d = id & 255;
    int n = (id >> 8) & 15;
    int b = id >> 12;
    float h = 0.f;
    for (int c = 0; c < NC; c++) {
        size_t ix = (((size_t)(b * NC + c) * 16) + n) * 256 + d;
        float Pv = Pb[ix];
        float Sv = Sb[ix];
        Sb[ix] = h;          // h_start for chunk c
        h = Pv * h + Sv;
    }
}

// ---------------- K4c: scan phase 3 — replay chunk from h_start, fuse D-skip + silu(z) gate ----------------
__global__ __launch_bounds__(256) void k_scan3(const float* __restrict__ dtb,
                                               const float* __restrict__ xin,
                                               const float* __restrict__ Bmb,
                                               const float* __restrict__ Cmb,
                                               const float* __restrict__ Alog,
                                               const float* __restrict__ Sb,
                                               const float* __restrict__ Dp,
                                               const float* __restrict__ xz,
                                               float* __restrict__ yg) {
    int blk = blockIdx.x;
    int b = blk / NC, ch = blk % NC;
    int d = threadIdx.x;
    int t0 = ch * CL;
    __shared__ float Bs[CL * 16], Cs[CL * 16];
    for (int idx = threadIdx.x; idx < CL * 16; idx += 256) {
        Bs[idx] = Bmb[((size_t)(b * L_SEQ + t0)) * 16 + idx];
        Cs[idx] = Cmb[((size_t)(b * L_SEQ + t0)) * 16 + idx];
    }
    float Ar[16], h[16];
    #pragma unroll
    for (int n = 0; n < 16; n++) Ar[n] = -__expf(Alog[d * 16 + n]);
    size_t base = ((size_t)(b * NC + ch) * 16) * 256 + d;
    #pragma unroll
    for (int n = 0; n < 16; n++) h[n] = Sb[base + (size_t)n * 256];
    float Dv = Dp[d];
    __syncthreads();
    for (int i = 0; i < CL; i++) {
        size_t p = (size_t)(b * L_SEQ + t0 + i);
        float dtv = dtb[p * 256 + d];
        float xv  = xin[p * 256 + d];
        float du = dtv * xv;
        float y = 0.f;
        #pragma unroll
        for (int n = 0; n < 16; n++) {
            float a = __expf(dtv * Ar[n]);
            h[n] = a * h[n] + du * Bs[i * 16 + n];
            y += h[n] * Cs[i * 16 + n];
        }
        float zv = xz[p * 512 + 256 + d];
        float sig = 1.f / (1.f + __expf(-zv));
        yg[p * 256 + d] = (y + xv * Dv) * (zv * sig);
    }
}

// ---------------- K5: out_proj GEMM with transposed output: out[b][c][t] = yg[b][t][:] . Wo[c][:] ----------------
__global__ __launch_bounds__(256) void k_outproj(const float* __restrict__ yg,
                                                 const float* __restrict__ wo,
                                                 float* __restrict__ out) {
    // grid: (BL/64, 128/64)
    __shared__ float As[64 * 65];  // [k][t_local]
    __shared__ float Bs[64 * 65];  // [k][c_local]
    int bl0 = blockIdx.x * 64;
    int b = bl0 / L_SEQ;
    int t0 = bl0 % L_SEQ;
    int c0 = blockIdx.y * 64;
    int tid = threadIdx.x;
    int tx = tid & 15, ty = tid >> 4;   // tx -> t (coalesced out writes), ty -> c

    float acc[4][4] = {};               // [t_off][c_off]
    for (int k0 = 0; k0 < 256; k0 += 64) {
        __syncthreads();
        for (int idx = tid; idx < 64 * 64; idx += 256) {
            int t = idx >> 6, kk = idx & 63;
            As[kk * 65 + t] = yg[(size_t)(bl0 + t) * 256 + k0 + kk];
        }
        for (int idx = tid; idx < 64 * 64; idx += 256) {
            int c = idx >> 6, kk = idx & 63;
            Bs[kk * 65 + c] = wo[(c0 + c) * 256 + k0 + kk];
        }
        __syncthreads();
        for (int k = 0; k < 64; k++) {
            float a[4], bb[4];
            #pragma unroll
            for (int ii = 0; ii < 4; ii++) a[ii] = As[k * 65 + tx * 4 + ii];
            #pragma unroll
            for (int jj = 0; jj < 4; jj++) bb[jj] = Bs[k * 65 + ty * 4 + jj];
            #pragma unroll
            for (int ii = 0; ii < 4; ii++)
                #pragma unroll
                for (int jj = 0; jj < 4; jj++) acc[ii][jj] += a[ii] * bb[jj];
        }
    }
    #pragma unroll
    for (int jj = 0; jj < 4; jj++) {
        int c = c0 + ty * 4 + jj;
        float4 v = make_float4(acc[0][jj], acc[1][jj], acc[2][jj], acc[3][jj]);
        *(float4*)&out[((size_t)(b * 128 + c)) * L_SEQ + t0 + tx * 4] = v;
    }
}

extern "C" void kernel_launch(void* const* d_in, const int* in_sizes, int n_in,
                              void* d_out, int out_size, void* d_ws, size_t ws_size,
                              hipStream_t stream) {
    const float* x    = (const float*)d_in[0];
    const float* nw   = (const float*)d_in[1];
    const float* nb   = (const float*)d_in[2];
    const float* w1   = (const float*)d_in[3];
    const float* cw   = (const float*)d_in[4];
    const float* cb   = (const float*)d_in[5];
    const float* wx   = (const float*)d_in[6];
    const float* wdt  = (const float*)d_in[7];
    const float* bdt  = (const float*)d_in[8];
    const float* Alog = (const float*)d_in[9];
    const float* Dp   = (const float*)d_in[10];
    const float* wo   = (const float*)d_in[11];
    float* out = (float*)d_out;

    float* ws   = (float*)d_ws;
    float* xz   = ws;                       // BL*512 = 16,777,216
    float* mu   = xz + (size_t)BL * 512;    // 32768
    float* rstd = mu + BL;                  // 32768
    float* xin  = rstd + BL;                // BL*256 = 8,388,608
    float* dtb  = xin + (size_t)BL * 256;   // 8,388,608
    float* Bmb  = dtb + (size_t)BL * 256;   // 524,288
    float* Cmb  = Bmb + (size_t)BL * 16;    // 524,288
    float* Pb   = Cmb + (size_t)BL * 16;    // 2*NC*16*256 = 4,194,304
    float* Sb   = Pb + (size_t)BATCH * NC * 16 * 256;  // 4,194,304
    float* yg   = Sb + (size_t)BATCH * NC * 16 * 256;  // 8,388,608

    k_ln_stats<<<BL / 256, 256, 0, stream>>>(x, mu, rstd);
    k_inproj<<<dim3(BL / 64, 512 / 64), 256, 0, stream>>>(x, mu, rstd, nw, nb, w1, xz);
    k_conv<<<BL, 256, 0, stream>>>(xz, cw, cb, xin);
    k_xproj<<<BL / 64, 256, 0, stream>>>(xin, wx, wdt, bdt, dtb, Bmb, Cmb);
    k_scan1<<<BATCH * NC, 256, 0, stream>>>(dtb, xin, Bmb, Alog, Pb, Sb);
    k_scan2<<<8192 / 256, 256, 0, stream>>>(Pb, Sb);
    k_scan3<<<BATCH * NC, 256, 0, stream>>>(dtb, xin, Bmb, Cmb, Alog, Sb, Dp, xz, yg);
    k_outproj<<<dim3(BL / 64, 128 / 64), 256, 0, stream>>>(yg, wo, out);
}

// Round 3
// 432.301 us; speedup vs baseline: 1.2672x; 1.0152x over previous
//
#include <hip/hip_runtime.h>
#include <math.h>

#define L_SEQ 16384
#define BATCH 2
#define BL (BATCH * L_SEQ)      // 32768
#define DIN 256                 // D_INNER
#define DIMC 128                // DIM
#define NST 16                  // D_STATE
#define DTR 8                   // DT_RANK
#define CL 32                   // chunk length for scan
#define NC (L_SEQ / CL)         // 512 chunks per batch

// ---------------- K0: layernorm stats (mean, rstd) per position ----------------
__global__ __launch_bounds__(256) void k_ln_stats(const float* __restrict__ x,
                                                  float* __restrict__ mu,
                                                  float* __restrict__ rstd) {
    int p = blockIdx.x * 256 + threadIdx.x;   // 0..BL-1
    int b = p / L_SEQ, l = p % L_SEQ;
    const float* xb = x + (size_t)b * DIMC * L_SEQ + l;
    float s = 0.f, s2 = 0.f;
    for (int c = 0; c < DIMC; c++) {
        float v = xb[(size_t)c * L_SEQ];
        s += v; s2 += v * v;
    }
    float m = s * (1.f / DIMC);
    float var = s2 * (1.f / DIMC) - m * m;
    mu[p] = m;
    rstd[p] = rsqrtf(var + 1e-6f);
}

// ---------------- K1: fused LN + in_proj GEMM: xz(BL x 512) = xn(BL x 128) @ W1^T ----------------
// LDS stride 68: 68*4=272 B, 272%16==0 -> every [c][quad] read is 16B-aligned ds_read_b128,
// and quad banks (tx*4)%32 give only 2-way aliasing (free on gfx950).
__global__ __launch_bounds__(256) void k_inproj(const float* __restrict__ x,
                                                const float* __restrict__ mu,
                                                const float* __restrict__ rstd,
                                                const float* __restrict__ nw,
                                                const float* __restrict__ nb,
                                                const float* __restrict__ w1,
                                                float* __restrict__ xz) {
    // grid: (BL/64, 512/64)
    __shared__ float As[128 * 68];  // [c][pos_local]
    __shared__ float Bs[128 * 68];  // [c][o_local]
    int bl0 = blockIdx.x * 64;
    int b = bl0 / L_SEQ;
    int l0 = bl0 % L_SEQ;
    int o0 = blockIdx.y * 64;
    int tid = threadIdx.x;

    for (int idx = tid; idx < 128 * 64; idx += 256) {
        int c = idx >> 6, i = idx & 63;
        float v = x[((size_t)b * DIMC + c) * L_SEQ + l0 + i];
        int p = bl0 + i;
        As[c * 68 + i] = (v - mu[p]) * rstd[p] * nw[c] + nb[c];
    }
    for (int idx = tid; idx < 64 * 128; idx += 256) {
        int o = idx >> 7, c = idx & 127;
        Bs[c * 68 + o] = w1[(o0 + o) * 128 + c];
    }
    __syncthreads();

    int tx = tid & 15, ty = tid >> 4;   // tx -> output dim o (coalesced writes), ty -> position
    float acc[4][4] = {};
    for (int c = 0; c < 128; c++) {
        float4 av = *(const float4*)&As[c * 68 + ty * 4];
        float4 bv = *(const float4*)&Bs[c * 68 + tx * 4];
        float a[4] = {av.x, av.y, av.z, av.w};
        float bb[4] = {bv.x, bv.y, bv.z, bv.w};
        #pragma unroll
        for (int ii = 0; ii < 4; ii++)
            #pragma unroll
            for (int jj = 0; jj < 4; jj++) acc[ii][jj] += a[ii] * bb[jj];
    }
    #pragma unroll
    for (int ii = 0; ii < 4; ii++) {
        int p = bl0 + ty * 4 + ii;
        float4 v = make_float4(acc[ii][0], acc[ii][1], acc[ii][2], acc[ii][3]);
        *(float4*)&xz[(size_t)p * 512 + o0 + tx * 4] = v;
    }
}

// ---------------- K2: causal depthwise conv (k=4) + silu -> x_in ----------------
__global__ __launch_bounds__(256) void k_conv(const float* __restrict__ xz,
                                              const float* __restrict__ cw,
                                              const float* __restrict__ cb,
                                              float* __restrict__ xin) {
    int p = blockIdx.x;          // 0..BL-1
    int d = threadIdx.x;         // 0..255
    int b = p / L_SEQ, t = p % L_SEQ;
    float acc = cb[d];
    #pragma unroll
    for (int k = 0; k < 4; k++) {
        int tt = t + k - 3;
        if (tt >= 0) acc += xz[((size_t)(b * L_SEQ + tt)) * 512 + d] * cw[d * 4 + k];
    }
    float sig = 1.f / (1.f + __expf(-acc));
    xin[(size_t)p * 256 + d] = acc * sig;
}

// ---------------- K3: x_proj GEMM (256->40, padded to 64) + fused dt_proj (8->256) + softplus ----
__global__ __launch_bounds__(256) void k_xproj(const float* __restrict__ xin,
                                               const float* __restrict__ wx,
                                               const float* __restrict__ wdt,
                                               const float* __restrict__ bdt,
                                               float* __restrict__ dtb,
                                               float* __restrict__ Bmb,
                                               float* __restrict__ Cmb) {
    __shared__ float Xs[128 * 68];  // [c][pos_local]
    __shared__ float Ws[128 * 68];  // [c][o_local] (o >= 40 zero-padded)
    __shared__ float Dt8[64 * 8];   // x_dbl[:, :8] staging for dt_proj
    int bl0 = blockIdx.x * 64;
    int tid = threadIdx.x;
    int tx = tid & 15, ty = tid >> 4;  // tx -> output quad, ty -> position quad

    float acc[4][4] = {};              // [pos_off][o_off]
    for (int c0 = 0; c0 < 256; c0 += 128) {
        __syncthreads();
        for (int idx = tid; idx < 128 * 64; idx += 256) {
            int c = idx & 127, i = idx >> 7;   // lane -> c : coalesced global read
            Xs[c * 68 + i] = xin[(size_t)(bl0 + i) * 256 + c0 + c];
        }
        for (int idx = tid; idx < 128 * 64; idx += 256) {
            int c = idx & 127, o = idx >> 7;
            Ws[c * 68 + o] = (o < 40) ? wx[o * 256 + c0 + c] : 0.f;
        }
        __syncthreads();
        for (int c = 0; c < 128; c++) {
            float4 av = *(const float4*)&Xs[c * 68 + ty * 4];
            float4 bv = *(const float4*)&Ws[c * 68 + tx * 4];
            float a[4] = {av.x, av.y, av.z, av.w};
            float bb[4] = {bv.x, bv.y, bv.z, bv.w};
            #pragma unroll
            for (int ii = 0; ii < 4; ii++)
                #pragma unroll
                for (int jj = 0; jj < 4; jj++) acc[ii][jj] += a[ii] * bb[jj];
        }
    }

    // Scatter outputs: o in [0,8) -> Dt8 (LDS), [8,24) -> Bm, [24,40) -> Cm
    __syncthreads();
    if (tx < 2) {
        #pragma unroll
        for (int ii = 0; ii < 4; ii++)
            #pragma unroll
            for (int jj = 0; jj < 4; jj++)
                Dt8[(ty * 4 + ii) * 8 + tx * 4 + jj] = acc[ii][jj];
    } else if (tx < 6) {
        #pragma unroll
        for (int ii = 0; ii < 4; ii++) {
            size_t p = (size_t)(bl0 + ty * 4 + ii);
            float4 v = make_float4(acc[ii][0], acc[ii][1], acc[ii][2], acc[ii][3]);
            *(float4*)&Bmb[p * 16 + (tx - 2) * 4] = v;
        }
    } else if (tx < 10) {
        #pragma unroll
        for (int ii = 0; ii < 4; ii++) {
            size_t p = (size_t)(bl0 + ty * 4 + ii);
            float4 v = make_float4(acc[ii][0], acc[ii][1], acc[ii][2], acc[ii][3]);
            *(float4*)&Cmb[p * 16 + (tx - 6) * 4] = v;
        }
    }
    __syncthreads();

    // dt_proj: each thread owns channel d = tid, loops the 64 positions
    int d = tid;
    float bias = bdt[d];
    float w8[8];
    #pragma unroll
    for (int r = 0; r < 8; r++) w8[r] = wdt[d * 8 + r];
    for (int p = 0; p < 64; p++) {
        float4 xa = *(float4*)&Dt8[p * 8];
        float4 xb = *(float4*)&Dt8[p * 8 + 4];
        float a = bias;
        a += xa.x * w8[0] + xa.y * w8[1] + xa.z * w8[2] + xa.w * w8[3];
        a += xb.x * w8[4] + xb.y * w8[5] + xb.z * w8[6] + xb.w * w8[7];
        float sp = (a > 20.f) ? a : log1pf(__expf(a));
        dtb[(size_t)(bl0 + p) * 256 + d] = sp;
    }
}

// ---------------- K4a: scan phase 1 — per-chunk products & local states ----------------
__global__ __launch_bounds__(256) void k_scan1(const float* __restrict__ dtb,
                                               const float* __restrict__ xin,
                                               const float* __restrict__ Bmb,
                                               const float* __restrict__ Alog,
                                               float* __restrict__ Pb,
                                               float* __restrict__ Sb) {
    int blk = blockIdx.x;            // BATCH*NC blocks
    int b = blk / NC, ch = blk % NC;
    int d = threadIdx.x;
    int t0 = ch * CL;
    __shared__ float Bs[CL * 16];
    for (int idx = threadIdx.x; idx < CL * 16; idx += 256)
        Bs[idx] = Bmb[((size_t)(b * L_SEQ + t0)) * 16 + idx];
    float Ar[16];
    #pragma unroll
    for (int n = 0; n < 16; n++) Ar[n] = -__expf(Alog[d * 16 + n]);
    float P[16], S[16];
    #pragma unroll
    for (int n = 0; n < 16; n++) { P[n] = 1.f; S[n] = 0.f; }
    __syncthreads();
    for (int i = 0; i < CL; i++) {
        size_t p = (size_t)(b * L_SEQ + t0 + i);
        float dtv = dtb[p * 256 + d];
        float xv  = xin[p * 256 + d];
        float du = dtv * xv;
        #pragma unroll
        for (int n = 0; n < 16; n++) {
            float a = __expf(dtv * Ar[n]);
            P[n] *= a;
            S[n] = a * S[n] + du * Bs[i * 16 + n];
        }
    }
    size_t base = ((size_t)(b * NC + ch) * 16) * 256 + d;
    #pragma unroll
    for (int n = 0; n < 16; n++) {
        Pb[base + (size_t)n * 256] = P[n];
        Sb[base + (size_t)n * 256] = S[n];
    }
}

// ---------------- K4b: scan phase 2 — sequential over chunks, Sb becomes h_start ----------------
__global__ __launch_bounds__(256) void k_scan2(const float* __restrict__ Pb,
                                               float* __restrict__ Sb) {
    int id = blockIdx.x * 256 + threadIdx.x;  // 0..8191: (b,n,d)
    int d = id & 255;
    int n = (id >> 8) & 15;
    int b = id >> 12;
    float h = 0.f;
    for (int c = 0; c < NC; c++) {
        size_t ix = (((size_t)(b * NC + c) * 16) + n) * 256 + d;
        float Pv = Pb[ix];
        float Sv = Sb[ix];
        Sb[ix] = h;          // h_start for chunk c
        h = Pv * h + Sv;
    }
}

// ---------------- K4c: scan phase 3 — replay chunk from h_start, fuse D-skip + silu(z) gate ----------------
__global__ __launch_bounds__(256) void k_scan3(const float* __restrict__ dtb,
                                               const float* __restrict__ xin,
                                               const float* __restrict__ Bmb,
                                               const float* __restrict__ Cmb,
                                               const float* __restrict__ Alog,
                                               const float* __restrict__ Sb,
                                               const float* __restrict__ Dp,
                                               const float* __restrict__ xz,
                                               float* __restrict__ yg) {
    int blk = blockIdx.x;
    int b = blk / NC, ch = blk % NC;
    int d = threadIdx.x;
    int t0 = ch * CL;
    __shared__ float Bs[CL * 16], Cs[CL * 16];
    for (int idx = threadIdx.x; idx < CL * 16; idx += 256) {
        Bs[idx] = Bmb[((size_t)(b * L_SEQ + t0)) * 16 + idx];
        Cs[idx] = Cmb[((size_t)(b * L_SEQ + t0)) * 16 + idx];
    }
    float Ar[16], h[16];
    #pragma unroll
    for (int n = 0; n < 16; n++) Ar[n] = -__expf(Alog[d * 16 + n]);
    size_t base = ((size_t)(b * NC + ch) * 16) * 256 + d;
    #pragma unroll
    for (int n = 0; n < 16; n++) h[n] = Sb[base + (size_t)n * 256];
    float Dv = Dp[d];
    __syncthreads();
    for (int i = 0; i < CL; i++) {
        size_t p = (size_t)(b * L_SEQ + t0 + i);
        float dtv = dtb[p * 256 + d];
        float xv  = xin[p * 256 + d];
        float du = dtv * xv;
        float y = 0.f;
        #pragma unroll
        for (int n = 0; n < 16; n++) {
            float a = __expf(dtv * Ar[n]);
            h[n] = a * h[n] + du * Bs[i * 16 + n];
            y += h[n] * Cs[i * 16 + n];
        }
        float zv = xz[p * 512 + 256 + d];
        float sig = 1.f / (1.f + __expf(-zv));
        yg[p * 256 + d] = (y + xv * Dv) * (zv * sig);
    }
}

// ---------------- K5: out_proj GEMM with transposed output: out[b][c][t] = yg[b][t][:] . Wo[c][:] ----------------
__global__ __launch_bounds__(256) void k_outproj(const float* __restrict__ yg,
                                                 const float* __restrict__ wo,
                                                 float* __restrict__ out) {
    // grid: (BL/64, 128/64)
    __shared__ float As[64 * 68];  // [k][t_local], stride 68 -> 16B-aligned b128 reads
    __shared__ float Bs[64 * 68];  // [k][c_local]
    int bl0 = blockIdx.x * 64;
    int b = bl0 / L_SEQ;
    int t0 = bl0 % L_SEQ;
    int c0 = blockIdx.y * 64;
    int tid = threadIdx.x;
    int tx = tid & 15, ty = tid >> 4;   // tx -> t (coalesced out writes), ty -> c

    float acc[4][4] = {};               // [t_off][c_off]
    for (int k0 = 0; k0 < 256; k0 += 64) {
        __syncthreads();
        for (int idx = tid; idx < 64 * 64; idx += 256) {
            int t = idx >> 6, kk = idx & 63;
            As[kk * 68 + t] = yg[(size_t)(bl0 + t) * 256 + k0 + kk];
        }
        for (int idx = tid; idx < 64 * 64; idx += 256) {
            int c = idx >> 6, kk = idx & 63;
            Bs[kk * 68 + c] = wo[(c0 + c) * 256 + k0 + kk];
        }
        __syncthreads();
        for (int k = 0; k < 64; k++) {
            float4 av = *(const float4*)&As[k * 68 + tx * 4];
            float4 bv = *(const float4*)&Bs[k * 68 + ty * 4];
            float a[4] = {av.x, av.y, av.z, av.w};
            float bb[4] = {bv.x, bv.y, bv.z, bv.w};
            #pragma unroll
            for (int ii = 0; ii < 4; ii++)
                #pragma unroll
                for (int jj = 0; jj < 4; jj++) acc[ii][jj] += a[ii] * bb[jj];
        }
    }
    #pragma unroll
    for (int jj = 0; jj < 4; jj++) {
        int c = c0 + ty * 4 + jj;
        float4 v = make_float4(acc[0][jj], acc[1][jj], acc[2][jj], acc[3][jj]);
        *(float4*)&out[((size_t)(b * 128 + c)) * L_SEQ + t0 + tx * 4] = v;
    }
}

extern "C" void kernel_launch(void* const* d_in, const int* in_sizes, int n_in,
                              void* d_out, int out_size, void* d_ws, size_t ws_size,
                              hipStream_t stream) {
    const float* x    = (const float*)d_in[0];
    const float* nw   = (const float*)d_in[1];
    const float* nb   = (const float*)d_in[2];
    const float* w1   = (const float*)d_in[3];
    const float* cw   = (const float*)d_in[4];
    const float* cb   = (const float*)d_in[5];
    const float* wx   = (const float*)d_in[6];
    const float* wdt  = (const float*)d_in[7];
    const float* bdt  = (const float*)d_in[8];
    const float* Alog = (const float*)d_in[9];
    const float* Dp   = (const float*)d_in[10];
    const float* wo   = (const float*)d_in[11];
    float* out = (float*)d_out;

    float* ws   = (float*)d_ws;
    float* xz   = ws;                       // BL*512 = 16,777,216
    float* mu   = xz + (size_t)BL * 512;    // 32768
    float* rstd = mu + BL;                  // 32768
    float* xin  = rstd + BL;                // BL*256 = 8,388,608
    float* dtb  = xin + (size_t)BL * 256;   // 8,388,608
    float* Bmb  = dtb + (size_t)BL * 256;   // 524,288
    float* Cmb  = Bmb + (size_t)BL * 16;    // 524,288
    float* Pb   = Cmb + (size_t)BL * 16;    // 2*NC*16*256 = 4,194,304
    float* Sb   = Pb + (size_t)BATCH * NC * 16 * 256;  // 4,194,304
    float* yg   = Sb + (size_t)BATCH * NC * 16 * 256;  // 8,388,608

    k_ln_stats<<<BL / 256, 256, 0, stream>>>(x, mu, rstd);
    k_inproj<<<dim3(BL / 64, 512 / 64), 256, 0, stream>>>(x, mu, rstd, nw, nb, w1, xz);
    k_conv<<<BL, 256, 0, stream>>>(xz, cw, cb, xin);
    k_xproj<<<BL / 64, 256, 0, stream>>>(xin, wx, wdt, bdt, dtb, Bmb, Cmb);
    k_scan1<<<BATCH * NC, 256, 0, stream>>>(dtb, xin, Bmb, Alog, Pb, Sb);
    k_scan2<<<8192 / 256, 256, 0, stream>>>(Pb, Sb);
    k_scan3<<<BATCH * NC, 256, 0, stream>>>(dtb, xin, Bmb, Cmb, Alog, Sb, Dp, xz, yg);
    k_outproj<<<dim3(BL / 64, 128 / 64), 256, 0, stream>>>(yg, wo, out);
}